// Round 5
// baseline (270.795 us; speedup 1.0000x reference)
//
#include <hip/hip_runtime.h>

typedef unsigned short ushort;
typedef unsigned int uint;
typedef __attribute__((ext_vector_type(8))) short short8v;
typedef __attribute__((ext_vector_type(4))) float floatx4;

// ---------------- problem constants ----------------
#define DIMK   8192
#define NPER   512
#define NROWS  2048
#define NCOLS  128
#define KSPLIT 8
#define KCHUNK 1024          // DIMK / KSPLIT
#define BK     64
#define BM     32
#define NIT    16            // KCHUNK / BK
#define SLICE_ELEMS 4194304.0

// ---------------- ws layout (bytes) ----------------
static const size_t STATS_OFF = 0;                                    // 16 doubles
static const size_t O2_OFF    = 128;                                  // 512 f32 (zeroed with stats)
static const size_t WB_OFF    = 4096;
static const size_t WB_BYTES  = (size_t)2 * 128 * DIMK * 2;           // 4 MB bf16 weights
static const size_t P_OFF     = WB_OFF + WB_BYTES;
static const size_t P_BYTES   = (size_t)2 * KSPLIT * NROWS * NCOLS * 4;  // 16.8 MB
static const size_t OUT2_OFF  = P_OFF + P_BYTES;                      // 512*512 f32
static const size_t IPSUM_OFF = OUT2_OFF + (size_t)512 * 512 * 4;     // 4*512 f32
static const size_t CTXB_OFF  = IPSUM_OFF + (size_t)4 * 512 * 4;      // 2048*64 f32
static const size_t WS_NEED   = CTXB_OFF + (size_t)2048 * 64 * 4;

__device__ __forceinline__ ushort f2bf(float x) {   // RNE f32->bf16
  uint u = __float_as_uint(x);
  return (ushort)((u + 0x7FFFu + ((u >> 16) & 1u)) >> 16);
}

// ---------------- K1: LN statistics (blocks 0..2047) + W->bf16 (blocks 2048..3071) ----------------
__global__ __launch_bounds__(256) void k_stats(const float* __restrict__ pic,
                                               const float* __restrict__ ctx,
                                               const float* __restrict__ Wp,
                                               const float* __restrict__ Wc,
                                               double* __restrict__ stats,
                                               ushort* __restrict__ Wb) {
  const int bid = blockIdx.x;
  const int tid = threadIdx.x;
  if (bid >= 2048) {
    const size_t i = ((size_t)(bid - 2048) * 256 + tid) * 8;
    const size_t HALF = (size_t)128 * DIMK;
    const float* src = (i < HALF) ? (Wp + i) : (Wc + (i - HALF));
    float4 a = *(const float4*)src;
    float4 b = *(const float4*)(src + 4);
    short8v v;
    v[0] = (short)f2bf(a.x); v[1] = (short)f2bf(a.y);
    v[2] = (short)f2bf(a.z); v[3] = (short)f2bf(a.w);
    v[4] = (short)f2bf(b.x); v[5] = (short)f2bf(b.y);
    v[6] = (short)f2bf(b.z); v[7] = (short)f2bf(b.w);
    *(short8v*)&Wb[i] = v;
    return;
  }
  const int s = bid >> 8;
  const int c = bid & 255;
  const int t = s >> 2, h = s & 3;
  const float4* p4 = reinterpret_cast<const float4*>(
      (t ? ctx : pic) + (size_t)h * NPER * DIMK + (size_t)c * 16384) + tid;

  float4 va[4], vb[4];
  float sA[4] = {0.f, 0.f, 0.f, 0.f};
  float qA[4] = {0.f, 0.f, 0.f, 0.f};

  auto ACC = [&](const float4* v) {
#pragma unroll
    for (int j = 0; j < 4; ++j) {
      const float4 w = v[j];
      sA[j] += (w.x + w.y) + (w.z + w.w);
      qA[j] += (w.x * w.x + w.y * w.y) + (w.z * w.z + w.w * w.w);
    }
  };

#pragma unroll
  for (int j = 0; j < 4; ++j) va[j] = p4[256 * j];
#pragma unroll
  for (int j = 0; j < 4; ++j) vb[j] = p4[256 * (4 + j)];
  __builtin_amdgcn_sched_barrier(0);
  ACC(va);
#pragma unroll
  for (int j = 0; j < 4; ++j) va[j] = p4[256 * (8 + j)];
  __builtin_amdgcn_sched_barrier(0);
  ACC(vb);
#pragma unroll
  for (int j = 0; j < 4; ++j) vb[j] = p4[256 * (12 + j)];
  __builtin_amdgcn_sched_barrier(0);
  ACC(va);
  ACC(vb);

  float sum = (sA[0] + sA[1]) + (sA[2] + sA[3]);
  float sq  = (qA[0] + qA[1]) + (qA[2] + qA[3]);
#pragma unroll
  for (int d = 1; d < 64; d <<= 1) {
    sum += __shfl_xor(sum, d);
    sq  += __shfl_xor(sq, d);
  }
  __shared__ float ps[4], pq[4];
  const int w = tid >> 6;
  if ((tid & 63) == 0) { ps[w] = sum; pq[w] = sq; }
  __syncthreads();
  if (tid == 0) {
    double S = (double)ps[0] + (double)ps[1] + (double)ps[2] + (double)ps[3];
    double Q = (double)pq[0] + (double)pq[1] + (double)pq[2] + (double)pq[3];
    atomicAdd(&stats[2 * s], S);
    atomicAdd(&stats[2 * s + 1], Q);
  }
}

// ---------------- K2: fused LN+spike+MFMA GEMM (split-K partials) ----------------
// grid (64 row-tiles, KSPLIT, 2) = 1024 blocks (4/CU), 256 threads = 4 waves
// BM=32 x BN=128; wave (wm,wn) does 16x64; single barrier per K-step.
__global__ __launch_bounds__(256, 4) void k_gemm(const float* __restrict__ pic,
                                                 const float* __restrict__ ctxin,
                                                 const float* __restrict__ gamma,
                                                 const float* __restrict__ lnbeta,
                                                 const ushort* __restrict__ Wb,
                                                 const double* __restrict__ stats,
                                                 float* __restrict__ P) {
  const int tid  = threadIdx.x;
  const int lane = tid & 63;
  const int wv   = tid >> 6;
  const int wm   = wv >> 1, wn = wv & 1;
  const int bx = blockIdx.x, ky = blockIdx.y, t = blockIdx.z;
  const float*  A  = t ? ctxin : pic;
  const ushort* Wt = Wb + (size_t)t * 128 * DIMK;
  const int row0 = bx * BM;

  const int sidx = t * 4 + (bx >> 4);        // 16 tiles of 32 rows per h
  double su = stats[2 * sidx], qu = stats[2 * sidx + 1];
  double dmean = su * (1.0 / SLICE_ELEMS);
  const float mean = (float)dmean;
  const float var  = (float)(qu * (1.0 / SLICE_ELEMS) - dmean * dmean);
  const float rstd = rsqrtf(var + 1e-5f);

  __shared__ __align__(16) ushort Asl[2][BM * BK];    // 4 KB x2
  __shared__ __align__(16) ushort Wsl[2][128 * BK];   // 16 KB x2

  const int k8 = (tid & 7) * 8;   // k offset within BK
  const int r0 = tid >> 3;        // 0..31

  const int kg8 = (lane >> 4) << 3;
  int abase, axor, bbase[4], bxor[4];
  {
    const int ra = wm * 16 + (lane & 15);
    abase = ra * BK; axor = (ra & 7) << 3;
  }
#pragma unroll
  for (int n = 0; n < 4; ++n) {
    const int rb = wn * 64 + n * 16 + (lane & 15);
    bbase[n] = rb * BK; bxor[n] = (rb & 7) << 3;
  }

  floatx4 acc[4];
  floatx4 zz = {0.f, 0.f, 0.f, 0.f};
#pragma unroll
  for (int n = 0; n < 4; ++n) acc[n] = zz;

  float4 xa[2]; uint4 xw[4];
  float4 g0, g1, bb0, bb1;

  auto LOAD = [&](int it) {
    const int kb = ky * KCHUNK + it * BK;
    const float* gp = gamma  + kb + k8;
    const float* bp = lnbeta + kb + k8;
    g0 = *(const float4*)gp;  g1 = *(const float4*)(gp + 4);
    bb0 = *(const float4*)bp; bb1 = *(const float4*)(bp + 4);
    const float* ap = A + (size_t)(row0 + r0) * DIMK + kb + k8;
    xa[0] = *(const float4*)ap;
    xa[1] = *(const float4*)(ap + 4);
#pragma unroll
    for (int c = 0; c < 4; ++c)
      xw[c] = *(const uint4*)(Wt + (size_t)(r0 + c * 32) * DIMK + kb + k8);
  };

  auto WRITE = [&](int buf) {
    {
      const int r = r0;
      float xs[8] = {xa[0].x, xa[0].y, xa[0].z, xa[0].w,
                     xa[1].x, xa[1].y, xa[1].z, xa[1].w};
      float gs[8] = {g0.x, g0.y, g0.z, g0.w, g1.x, g1.y, g1.z, g1.w};
      float bs[8] = {bb0.x, bb0.y, bb0.z, bb0.w, bb1.x, bb1.y, bb1.z, bb1.w};
      short8v sv;
#pragma unroll
      for (int j = 0; j < 8; ++j)
        sv[j] = (short)(((xs[j] - mean) * rstd * gs[j] + bs[j] > 1.0f) ? 0x3F80 : 0);
      *(short8v*)&Asl[buf][r * BK + (k8 ^ ((r & 7) << 3))] = sv;
    }
#pragma unroll
    for (int c = 0; c < 4; ++c) {
      const int r = r0 + c * 32;
      *(uint4*)&Wsl[buf][r * BK + (k8 ^ ((r & 7) << 3))] = xw[c];
    }
  };

  auto COMPUTE = [&](int buf) {
#pragma unroll
    for (int ks = 0; ks < 2; ++ks) {
      short8v af, bfr[4];
      af = *(const short8v*)&Asl[buf][abase + ((ks * 32 + kg8) ^ axor)];
#pragma unroll
      for (int n = 0; n < 4; ++n)
        bfr[n] = *(const short8v*)&Wsl[buf][bbase[n] + ((ks * 32 + kg8) ^ bxor[n])];
#pragma unroll
      for (int n = 0; n < 4; ++n)
        acc[n] = __builtin_amdgcn_mfma_f32_16x16x32_bf16(af, bfr[n], acc[n], 0, 0, 0);
    }
  };

  LOAD(0);
  WRITE(0);
  __syncthreads();
  // single barrier per K-step: compute(cur) and write(next) touch different
  // buffers; cross-iteration hazards (write(b) vs compute(b) of the previous
  // iteration) are covered by the one trailing sync.
#pragma unroll 2
  for (int it = 0; it < NIT - 1; ++it) {
    LOAD(it + 1);
    COMPUTE(it & 1);
    WRITE((it + 1) & 1);
    __syncthreads();
  }
  COMPUTE((NIT - 1) & 1);

  // C/D layout: col = lane&15, row = (lane>>4)*4 + j
  float* Pt = P + ((size_t)(t * KSPLIT + ky) * NROWS + row0) * NCOLS;
  const int gr = wm * 16 + ((lane >> 4) << 2);
#pragma unroll
  for (int n = 0; n < 4; ++n) {
    const int gc = wn * 64 + n * 16 + (lane & 15);
#pragma unroll
    for (int j = 0; j < 4; ++j)
      Pt[(size_t)(gr + j) * NCOLS + gc] = acc[n][j];
  }
}

// ---------------- K3: per-row epilogue, vectorized (8 rows/block) ----------------
__global__ __launch_bounds__(256) void k_row(const float* __restrict__ P,
                                             const float* __restrict__ b_pic,
                                             const float* __restrict__ b_ctx,
                                             float* __restrict__ out2,
                                             float* __restrict__ ipsum,
                                             float* __restrict__ ctxbuf) {
  const int tid = threadIdx.x;
  const int q = tid >> 5;
  const int u = tid & 31;
  const int r = blockIdx.x * 8 + q;
  const int o4 = u * 4;

  float4 ip = ((const float4*)b_pic)[u];
  float4 cv = ((const float4*)b_ctx)[u];
#pragma unroll
  for (int ks = 0; ks < KSPLIT; ++ks) {
    const float4 a = *(const float4*)&P[((size_t)ks * NROWS + r) * NCOLS + o4];
    const float4 b = *(const float4*)&P[((size_t)(KSPLIT + ks) * NROWS + r) * NCOLS + o4];
    ip.x += a.x; ip.y += a.y; ip.z += a.z; ip.w += a.w;
    cv.x += b.x; cv.y += b.y; cv.z += b.z; cv.w += b.w;
  }
  ip.x *= 0.125f; ip.y *= 0.125f; ip.z *= 0.125f; ip.w *= 0.125f;

  float clo = (u < 16) ? (cv.x + cv.y) + (cv.z + cv.w) : 0.f;
  float chi = (u >= 16) ? (cv.x + cv.y) + (cv.z + cv.w) : 0.f;
  float ipp = (ip.x + ip.y) + (ip.z + ip.w);
#pragma unroll
  for (int d = 1; d < 32; d <<= 1) {
    clo += __shfl_xor(clo, d);
    chi += __shfl_xor(chi, d);
    ipp += __shfl_xor(ipp, d);
  }
  const float ic_s = clo, v_s = chi;
  if (u == 0) ipsum[r] = ipp;

  float4 sim;
  sim.x = ip.x * ic_s; sim.y = ip.y * ic_s; sim.z = ip.z * ic_s; sim.w = ip.w * ic_s;
  float m = fmaxf(fmaxf(sim.x, sim.y), fmaxf(sim.z, sim.w));
#pragma unroll
  for (int d = 1; d < 32; d <<= 1) m = fmaxf(m, __shfl_xor(m, d));
  float4 e;
  e.x = __expf(sim.x - m); e.y = __expf(sim.y - m);
  e.z = __expf(sim.z - m); e.w = __expf(sim.w - m);
  float es = (e.x + e.y) + (e.z + e.w);
#pragma unroll
  for (int d = 1; d < 32; d <<= 1) es += __shfl_xor(es, d);
  const float sc = v_s / es;
  float4 outv;
  outv.x = e.x * sc; outv.y = e.y * sc; outv.z = e.z * sc; outv.w = e.w * sc;

  const int hh = r >> 9, n = r & 511;
  *(float4*)&out2[(size_t)n * 512 + hh * 128 + o4] = outv;
  if (u < 16) *(float4*)&ctxbuf[(size_t)r * 64 + o4] = cv;
}

// ---------------- K4: conv chain as w_eff matvec (8 blocks, atomic) ----------------
__global__ __launch_bounds__(512) void k_mid(const float* __restrict__ out2,
                                             const float* __restrict__ c1w,
                                             const float* __restrict__ c1b,
                                             const float* __restrict__ c2w,
                                             const float* __restrict__ c2b,
                                             float* __restrict__ o2buf) {
  const int b = blockIdx.x;
  const int tid = threadIdx.x;
  __shared__ float wsh[64];
  __shared__ float c2s[32];
  if (tid < 32) c2s[tid] = c2w[tid];
  __syncthreads();
  if (tid < 64) {
    const int n = b * 64 + tid;
    float a = 0.f;
#pragma unroll
    for (int o = 0; o < 32; ++o) a += c2s[o] * c1w[o * 512 + n];
    wsh[tid] = a;
  }
  __syncthreads();
  float acc = 0.f;
#pragma unroll 8
  for (int ucnt = 0; ucnt < 64; ++ucnt)
    acc += out2[(size_t)(b * 64 + ucnt) * 512 + tid] * wsh[ucnt];
  if (b == 0) {
    float beff = c2b[0];
#pragma unroll
    for (int o = 0; o < 32; ++o) beff += c2s[o] * c1b[o];
    acc += beff;
  }
  atomicAdd(&o2buf[tid], acc);
}

// ---------------- K5: fc matvec + broadcast + interp + relu + ic_sum ----------------
__global__ __launch_bounds__(64) void k_final(const float* __restrict__ o2buf,
                                              const float* __restrict__ fcw,
                                              const float* __restrict__ fcb,
                                              const float* __restrict__ ipsum,
                                              const float* __restrict__ ctxbuf,
                                              float* __restrict__ out) {
  const int i = blockIdx.x;
  const int j = threadIdx.x;
  float a = 0.f;
#pragma unroll
  for (int uu = 0; uu < 8; ++uu) {
    const int k = j * 8 + uu;
    a += o2buf[k] * fcw[(size_t)i * 512 + k];
  }
#pragma unroll
  for (int d = 1; d < 64; d <<= 1) a += __shfl_xor(a, d);
  const float o3 = a + fcb[i];

  float src = (j + 0.5f) * (4.0f / 64.0f) - 0.5f;
  src = fmaxf(src, 0.0f);
  int i0 = (int)floorf(src);
  if (i0 > 3) i0 = 3;
  const int i1 = (i0 + 1 < 3) ? i0 + 1 : 3;
  const float w = src - (float)i0;

  const float v0 = o3 + ipsum[i0 * 512 + i];
  const float v1 = o3 + ipsum[i1 * 512 + i];
  float v = v0 * (1.0f - w) + v1 * w;
  v = fmaxf(v, 0.0f);

  float ics = 0.f;
#pragma unroll
  for (int hh2 = 0; hh2 < 4; ++hh2) ics += ctxbuf[((size_t)hh2 * 512 + i) * 64 + j];
  out[(size_t)i * 64 + j] = fmaxf(v + ics, 0.0f);
}

// ---------------- launch ----------------
extern "C" void kernel_launch(void* const* d_in, const int* in_sizes, int n_in,
                              void* d_out, int out_size, void* d_ws, size_t ws_size,
                              hipStream_t stream) {
  const float* pic    = (const float*)d_in[0];
  const float* ctx    = (const float*)d_in[1];
  const float* gamma  = (const float*)d_in[2];
  const float* lnbeta = (const float*)d_in[3];
  const float* Wp     = (const float*)d_in[4];
  const float* bp     = (const float*)d_in[5];
  const float* Wc     = (const float*)d_in[6];
  const float* bc     = (const float*)d_in[7];
  const float* c1w    = (const float*)d_in[8];
  const float* c1b    = (const float*)d_in[9];
  const float* c2w    = (const float*)d_in[10];
  const float* c2b    = (const float*)d_in[11];
  const float* fcw    = (const float*)d_in[12];
  const float* fcb    = (const float*)d_in[13];
  float* out = (float*)d_out;

  if (ws_size < WS_NEED) return;

  char* ws = (char*)d_ws;
  double* stats = (double*)(ws + STATS_OFF);
  float* o2buf  = (float*)(ws + O2_OFF);
  ushort* Wb    = (ushort*)(ws + WB_OFF);
  float* P      = (float*)(ws + P_OFF);
  float* out2   = (float*)(ws + OUT2_OFF);
  float* ipsum  = (float*)(ws + IPSUM_OFF);
  float* ctxbuf = (float*)(ws + CTXB_OFF);

  hipMemsetAsync(ws, 0, 128 + 512 * 4, stream);   // stats + o2buf
  k_stats<<<3072, 256, 0, stream>>>(pic, ctx, Wp, Wc, stats, Wb);
  k_gemm<<<dim3(64, KSPLIT, 2), 256, 0, stream>>>(pic, ctx, gamma, lnbeta, Wb, stats, P);
  k_row<<<256, 256, 0, stream>>>(P, bp, bc, out2, ipsum, ctxbuf);
  k_mid<<<8, 512, 0, stream>>>(out2, c1w, c1b, c2w, c2b, o2buf);
  k_final<<<512, 64, 0, stream>>>(o2buf, fcw, fcb, ipsum, ctxbuf, out);
}

// Round 6
// 265.146 us; speedup vs baseline: 1.0213x; 1.0213x over previous
//
#include <hip/hip_runtime.h>

typedef unsigned short ushort;
typedef unsigned int uint;
typedef __attribute__((ext_vector_type(8))) short short8v;
typedef __attribute__((ext_vector_type(4))) float floatx4;

// ---------------- problem constants ----------------
#define DIMK   8192
#define NPER   512
#define NROWS  2048
#define NCOLS  128
#define KSPLIT 8
#define KCHUNK 1024          // DIMK / KSPLIT
#define BK     64
#define BM     64
#define NIT    16            // KCHUNK / BK
#define SLICE_ELEMS 4194304.0

// ---------------- ws layout (bytes) ----------------
static const size_t STATS_OFF = 0;                                    // 16 doubles
static const size_t O2_OFF    = 128;                                  // 512 f32 (zeroed with stats)
static const size_t WB_OFF    = 4096;
static const size_t WB_BYTES  = (size_t)2 * 128 * DIMK * 2;           // 4 MB bf16 weights
static const size_t P_OFF     = WB_OFF + WB_BYTES;
static const size_t P_BYTES   = (size_t)2 * KSPLIT * NROWS * NCOLS * 4;  // 16.8 MB
static const size_t OUT2_OFF  = P_OFF + P_BYTES;                      // 512*512 f32
static const size_t IPSUM_OFF = OUT2_OFF + (size_t)512 * 512 * 4;     // 4*512 f32
static const size_t CTXB_OFF  = IPSUM_OFF + (size_t)4 * 512 * 4;      // 2048*64 f32
static const size_t WS_NEED   = CTXB_OFF + (size_t)2048 * 64 * 4;

__device__ __forceinline__ ushort f2bf(float x) {   // RNE f32->bf16
  uint u = __float_as_uint(x);
  return (ushort)((u + 0x7FFFu + ((u >> 16) & 1u)) >> 16);
}

// ---------------- K1: LN statistics (blocks 0..2047) + W->bf16 (blocks 2048..3071) ----------------
// stats blocks: 16-deep load burst (all loads in flight before any accumulation)
__global__ __launch_bounds__(256) void k_stats(const float* __restrict__ pic,
                                               const float* __restrict__ ctx,
                                               const float* __restrict__ Wp,
                                               const float* __restrict__ Wc,
                                               double* __restrict__ stats,
                                               ushort* __restrict__ Wb) {
  const int bid = blockIdx.x;
  const int tid = threadIdx.x;
  if (bid >= 2048) {
    const size_t i = ((size_t)(bid - 2048) * 256 + tid) * 8;
    const size_t HALF = (size_t)128 * DIMK;
    const float* src = (i < HALF) ? (Wp + i) : (Wc + (i - HALF));
    float4 a = *(const float4*)src;
    float4 b = *(const float4*)(src + 4);
    short8v v;
    v[0] = (short)f2bf(a.x); v[1] = (short)f2bf(a.y);
    v[2] = (short)f2bf(a.z); v[3] = (short)f2bf(a.w);
    v[4] = (short)f2bf(b.x); v[5] = (short)f2bf(b.y);
    v[6] = (short)f2bf(b.z); v[7] = (short)f2bf(b.w);
    *(short8v*)&Wb[i] = v;
    return;
  }
  const int s = bid >> 8;
  const int c = bid & 255;
  const int t = s >> 2, h = s & 3;
  const float4* p4 = reinterpret_cast<const float4*>(
      (t ? ctx : pic) + (size_t)h * NPER * DIMK + (size_t)c * 16384) + tid;

  // issue ALL 16 loads before any math; fence keeps them above the accumulation
  float4 v[16];
#pragma unroll
  for (int j = 0; j < 16; ++j) v[j] = p4[256 * j];
  __builtin_amdgcn_sched_barrier(0);

  float sA[4] = {0.f, 0.f, 0.f, 0.f};
  float qA[4] = {0.f, 0.f, 0.f, 0.f};
#pragma unroll
  for (int j = 0; j < 16; j += 4) {
#pragma unroll
    for (int u = 0; u < 4; ++u) {
      const float4 w = v[j + u];
      sA[u] += (w.x + w.y) + (w.z + w.w);
      qA[u] += (w.x * w.x + w.y * w.y) + (w.z * w.z + w.w * w.w);
    }
  }

  float sum = (sA[0] + sA[1]) + (sA[2] + sA[3]);
  float sq  = (qA[0] + qA[1]) + (qA[2] + qA[3]);
#pragma unroll
  for (int d = 1; d < 64; d <<= 1) {
    sum += __shfl_xor(sum, d);
    sq  += __shfl_xor(sq, d);
  }
  __shared__ float ps[4], pq[4];
  const int w = tid >> 6;
  if ((tid & 63) == 0) { ps[w] = sum; pq[w] = sq; }
  __syncthreads();
  if (tid == 0) {
    double S = (double)ps[0] + (double)ps[1] + (double)ps[2] + (double)ps[3];
    double Q = (double)pq[0] + (double)pq[1] + (double)pq[2] + (double)pq[3];
    atomicAdd(&stats[2 * s], S);
    atomicAdd(&stats[2 * s + 1], Q);
  }
}

// ---------------- K2: fused LN+spike+MFMA GEMM (split-K partials) ----------------
// grid (32 row-tiles, KSPLIT, 2) = 512 blocks, 256 threads = 4 waves (2x2 of 32x64)
// single barrier per K-step; LDS-staged coalesced C-store.
__global__ __launch_bounds__(256, 2) void k_gemm(const float* __restrict__ pic,
                                                 const float* __restrict__ ctxin,
                                                 const float* __restrict__ gamma,
                                                 const float* __restrict__ lnbeta,
                                                 const ushort* __restrict__ Wb,
                                                 const double* __restrict__ stats,
                                                 float* __restrict__ P) {
  const int tid  = threadIdx.x;
  const int lane = tid & 63;
  const int wv   = tid >> 6;
  const int wm   = wv >> 1, wn = wv & 1;
  const int bx = blockIdx.x, ky = blockIdx.y, t = blockIdx.z;
  const float*  A  = t ? ctxin : pic;
  const ushort* Wt = Wb + (size_t)t * 128 * DIMK;
  const int row0 = bx * BM;

  const int sidx = t * 4 + (bx >> 3);        // 8 tiles of 64 rows per h
  double su = stats[2 * sidx], qu = stats[2 * sidx + 1];
  double dmean = su * (1.0 / SLICE_ELEMS);
  const float mean = (float)dmean;
  const float var  = (float)(qu * (1.0 / SLICE_ELEMS) - dmean * dmean);
  const float rstd = rsqrtf(var + 1e-5f);

  __shared__ __align__(16) ushort Asl[2][BM * BK];    // 8 KB x2
  __shared__ __align__(16) ushort Wsl[2][128 * BK];   // 16 KB x2
  __shared__ __align__(16) float  Cst[BM][132];       // 33.8 KB (padded, 16B-aligned rows)

  const int k8 = (tid & 7) * 8;
  const int r0 = tid >> 3;        // 0..31

  const int kg8 = (lane >> 4) << 3;
  int abase[2], axor[2], bbase[4], bxor[4];
#pragma unroll
  for (int m = 0; m < 2; ++m) {
    const int ra = wm * 32 + m * 16 + (lane & 15);
    abase[m] = ra * BK; axor[m] = (ra & 7) << 3;
  }
#pragma unroll
  for (int n = 0; n < 4; ++n) {
    const int rb = wn * 64 + n * 16 + (lane & 15);
    bbase[n] = rb * BK; bxor[n] = (rb & 7) << 3;
  }

  floatx4 acc[2][4];
  floatx4 zz = {0.f, 0.f, 0.f, 0.f};
#pragma unroll
  for (int m = 0; m < 2; ++m)
#pragma unroll
    for (int n = 0; n < 4; ++n) acc[m][n] = zz;

  float4 xa[2][2]; uint4 xw[4];
  float4 g0, g1, bb0, bb1;

  auto LOAD = [&](int it) {
    const int kb = ky * KCHUNK + it * BK;
    const float* gp = gamma  + kb + k8;
    const float* bp = lnbeta + kb + k8;
    g0 = *(const float4*)gp;  g1 = *(const float4*)(gp + 4);
    bb0 = *(const float4*)bp; bb1 = *(const float4*)(bp + 4);
#pragma unroll
    for (int c = 0; c < 2; ++c) {
      const float* ap = A + (size_t)(row0 + r0 + c * 32) * DIMK + kb + k8;
      xa[c][0] = *(const float4*)ap;
      xa[c][1] = *(const float4*)(ap + 4);
    }
#pragma unroll
    for (int c = 0; c < 4; ++c)
      xw[c] = *(const uint4*)(Wt + (size_t)(r0 + c * 32) * DIMK + kb + k8);
  };

  auto WRITE = [&](int buf) {
#pragma unroll
    for (int c = 0; c < 2; ++c) {
      const int r = r0 + c * 32;
      float xs[8] = {xa[c][0].x, xa[c][0].y, xa[c][0].z, xa[c][0].w,
                     xa[c][1].x, xa[c][1].y, xa[c][1].z, xa[c][1].w};
      float gs[8] = {g0.x, g0.y, g0.z, g0.w, g1.x, g1.y, g1.z, g1.w};
      float bs[8] = {bb0.x, bb0.y, bb0.z, bb0.w, bb1.x, bb1.y, bb1.z, bb1.w};
      short8v sv;
#pragma unroll
      for (int j = 0; j < 8; ++j)
        sv[j] = (short)(((xs[j] - mean) * rstd * gs[j] + bs[j] > 1.0f) ? 0x3F80 : 0);
      *(short8v*)&Asl[buf][r * BK + (k8 ^ ((r & 7) << 3))] = sv;
    }
#pragma unroll
    for (int c = 0; c < 4; ++c) {
      const int r = r0 + c * 32;
      *(uint4*)&Wsl[buf][r * BK + (k8 ^ ((r & 7) << 3))] = xw[c];
    }
  };

  auto COMPUTE = [&](int buf) {
#pragma unroll
    for (int ks = 0; ks < 2; ++ks) {
      short8v af[2], bfr[4];
#pragma unroll
      for (int m = 0; m < 2; ++m)
        af[m] = *(const short8v*)&Asl[buf][abase[m] + ((ks * 32 + kg8) ^ axor[m])];
#pragma unroll
      for (int n = 0; n < 4; ++n)
        bfr[n] = *(const short8v*)&Wsl[buf][bbase[n] + ((ks * 32 + kg8) ^ bxor[n])];
#pragma unroll
      for (int m = 0; m < 2; ++m)
#pragma unroll
        for (int n = 0; n < 4; ++n)
          acc[m][n] = __builtin_amdgcn_mfma_f32_16x16x32_bf16(af[m], bfr[n], acc[m][n], 0, 0, 0);
    }
  };

  LOAD(0);
  WRITE(0);
  __syncthreads();
  // single barrier per K-step: compute(cur) and write(next) touch different
  // buffers; cross-iteration hazards are covered by the one trailing sync
  // (ds_reads are consumed by MFMAs before each wave reaches the barrier).
#pragma unroll 2
  for (int it = 0; it < NIT - 1; ++it) {
    LOAD(it + 1);
    COMPUTE(it & 1);
    WRITE((it + 1) & 1);
    __syncthreads();
  }
  COMPUTE((NIT - 1) & 1);

  // stage C in LDS (C/D layout: col = lane&15, row = (lane>>4)*4 + j),
  // then store full 512B rows coalesced.
#pragma unroll
  for (int m = 0; m < 2; ++m) {
    const int gr = wm * 32 + m * 16 + ((lane >> 4) << 2);
#pragma unroll
    for (int n = 0; n < 4; ++n) {
      const int gc = wn * 64 + n * 16 + (lane & 15);
#pragma unroll
      for (int j = 0; j < 4; ++j)
        Cst[gr + j][gc] = acc[m][n][j];
    }
  }
  __syncthreads();
  float* Pt = P + ((size_t)(t * KSPLIT + ky) * NROWS + row0) * NCOLS;
  const int rr = tid >> 2;            // 0..63
  const int cq = (tid & 3) * 32;      // 0,32,64,96
  float* dst = Pt + (size_t)rr * NCOLS + cq;
#pragma unroll
  for (int i = 0; i < 8; ++i)
    *(float4*)(dst + i * 4) = *(const float4*)&Cst[rr][cq + i * 4];
}

// ---------------- K3: per-row epilogue, vectorized (8 rows/block) ----------------
__global__ __launch_bounds__(256) void k_row(const float* __restrict__ P,
                                             const float* __restrict__ b_pic,
                                             const float* __restrict__ b_ctx,
                                             float* __restrict__ out2,
                                             float* __restrict__ ipsum,
                                             float* __restrict__ ctxbuf) {
  const int tid = threadIdx.x;
  const int q = tid >> 5;
  const int u = tid & 31;
  const int r = blockIdx.x * 8 + q;
  const int o4 = u * 4;

  float4 ip = ((const float4*)b_pic)[u];
  float4 cv = ((const float4*)b_ctx)[u];
#pragma unroll
  for (int ks = 0; ks < KSPLIT; ++ks) {
    const float4 a = *(const float4*)&P[((size_t)ks * NROWS + r) * NCOLS + o4];
    const float4 b = *(const float4*)&P[((size_t)(KSPLIT + ks) * NROWS + r) * NCOLS + o4];
    ip.x += a.x; ip.y += a.y; ip.z += a.z; ip.w += a.w;
    cv.x += b.x; cv.y += b.y; cv.z += b.z; cv.w += b.w;
  }
  ip.x *= 0.125f; ip.y *= 0.125f; ip.z *= 0.125f; ip.w *= 0.125f;

  float clo = (u < 16) ? (cv.x + cv.y) + (cv.z + cv.w) : 0.f;
  float chi = (u >= 16) ? (cv.x + cv.y) + (cv.z + cv.w) : 0.f;
  float ipp = (ip.x + ip.y) + (ip.z + ip.w);
#pragma unroll
  for (int d = 1; d < 32; d <<= 1) {
    clo += __shfl_xor(clo, d);
    chi += __shfl_xor(chi, d);
    ipp += __shfl_xor(ipp, d);
  }
  const float ic_s = clo, v_s = chi;
  if (u == 0) ipsum[r] = ipp;

  float4 sim;
  sim.x = ip.x * ic_s; sim.y = ip.y * ic_s; sim.z = ip.z * ic_s; sim.w = ip.w * ic_s;
  float m = fmaxf(fmaxf(sim.x, sim.y), fmaxf(sim.z, sim.w));
#pragma unroll
  for (int d = 1; d < 32; d <<= 1) m = fmaxf(m, __shfl_xor(m, d));
  float4 e;
  e.x = __expf(sim.x - m); e.y = __expf(sim.y - m);
  e.z = __expf(sim.z - m); e.w = __expf(sim.w - m);
  float es = (e.x + e.y) + (e.z + e.w);
#pragma unroll
  for (int d = 1; d < 32; d <<= 1) es += __shfl_xor(es, d);
  const float sc = v_s / es;
  float4 outv;
  outv.x = e.x * sc; outv.y = e.y * sc; outv.z = e.z * sc; outv.w = e.w * sc;

  const int hh = r >> 9, n = r & 511;
  *(float4*)&out2[(size_t)n * 512 + hh * 128 + o4] = outv;
  if (u < 16) *(float4*)&ctxbuf[(size_t)r * 64 + o4] = cv;
}

// ---------------- K4: conv chain as w_eff matvec (8 blocks, atomic) ----------------
__global__ __launch_bounds__(512) void k_mid(const float* __restrict__ out2,
                                             const float* __restrict__ c1w,
                                             const float* __restrict__ c1b,
                                             const float* __restrict__ c2w,
                                             const float* __restrict__ c2b,
                                             float* __restrict__ o2buf) {
  const int b = blockIdx.x;
  const int tid = threadIdx.x;
  __shared__ float wsh[64];
  __shared__ float c2s[32];
  if (tid < 32) c2s[tid] = c2w[tid];
  __syncthreads();
  if (tid < 64) {
    const int n = b * 64 + tid;
    float a = 0.f;
#pragma unroll
    for (int o = 0; o < 32; ++o) a += c2s[o] * c1w[o * 512 + n];
    wsh[tid] = a;
  }
  __syncthreads();
  float acc = 0.f;
#pragma unroll 8
  for (int ucnt = 0; ucnt < 64; ++ucnt)
    acc += out2[(size_t)(b * 64 + ucnt) * 512 + tid] * wsh[ucnt];
  if (b == 0) {
    float beff = c2b[0];
#pragma unroll
    for (int o = 0; o < 32; ++o) beff += c2s[o] * c1b[o];
    acc += beff;
  }
  atomicAdd(&o2buf[tid], acc);
}

// ---------------- K5: fc matvec + broadcast + interp + relu + ic_sum ----------------
__global__ __launch_bounds__(64) void k_final(const float* __restrict__ o2buf,
                                              const float* __restrict__ fcw,
                                              const float* __restrict__ fcb,
                                              const float* __restrict__ ipsum,
                                              const float* __restrict__ ctxbuf,
                                              float* __restrict__ out) {
  const int i = blockIdx.x;
  const int j = threadIdx.x;
  float a = 0.f;
#pragma unroll
  for (int uu = 0; uu < 8; ++uu) {
    const int k = j * 8 + uu;
    a += o2buf[k] * fcw[(size_t)i * 512 + k];
  }
#pragma unroll
  for (int d = 1; d < 64; d <<= 1) a += __shfl_xor(a, d);
  const float o3 = a + fcb[i];

  float src = (j + 0.5f) * (4.0f / 64.0f) - 0.5f;
  src = fmaxf(src, 0.0f);
  int i0 = (int)floorf(src);
  if (i0 > 3) i0 = 3;
  const int i1 = (i0 + 1 < 3) ? i0 + 1 : 3;
  const float w = src - (float)i0;

  const float v0 = o3 + ipsum[i0 * 512 + i];
  const float v1 = o3 + ipsum[i1 * 512 + i];
  float v = v0 * (1.0f - w) + v1 * w;
  v = fmaxf(v, 0.0f);

  float ics = 0.f;
#pragma unroll
  for (int hh2 = 0; hh2 < 4; ++hh2) ics += ctxbuf[((size_t)hh2 * 512 + i) * 64 + j];
  out[(size_t)i * 64 + j] = fmaxf(v + ics, 0.0f);
}

// ---------------- launch ----------------
extern "C" void kernel_launch(void* const* d_in, const int* in_sizes, int n_in,
                              void* d_out, int out_size, void* d_ws, size_t ws_size,
                              hipStream_t stream) {
  const float* pic    = (const float*)d_in[0];
  const float* ctx    = (const float*)d_in[1];
  const float* gamma  = (const float*)d_in[2];
  const float* lnbeta = (const float*)d_in[3];
  const float* Wp     = (const float*)d_in[4];
  const float* bp     = (const float*)d_in[5];
  const float* Wc     = (const float*)d_in[6];
  const float* bc     = (const float*)d_in[7];
  const float* c1w    = (const float*)d_in[8];
  const float* c1b    = (const float*)d_in[9];
  const float* c2w    = (const float*)d_in[10];
  const float* c2b    = (const float*)d_in[11];
  const float* fcw    = (const float*)d_in[12];
  const float* fcb    = (const float*)d_in[13];
  float* out = (float*)d_out;

  if (ws_size < WS_NEED) return;

  char* ws = (char*)d_ws;
  double* stats = (double*)(ws + STATS_OFF);
  float* o2buf  = (float*)(ws + O2_OFF);
  ushort* Wb    = (ushort*)(ws + WB_OFF);
  float* P      = (float*)(ws + P_OFF);
  float* out2   = (float*)(ws + OUT2_OFF);
  float* ipsum  = (float*)(ws + IPSUM_OFF);
  float* ctxbuf = (float*)(ws + CTXB_OFF);

  hipMemsetAsync(ws, 0, 128 + 512 * 4, stream);   // stats + o2buf
  k_stats<<<3072, 256, 0, stream>>>(pic, ctx, Wp, Wc, stats, Wb);
  k_gemm<<<dim3(32, KSPLIT, 2), 256, 0, stream>>>(pic, ctx, gamma, lnbeta, Wb, stats, P);
  k_row<<<256, 256, 0, stream>>>(P, bp, bc, out2, ipsum, ctxbuf);
  k_mid<<<8, 512, 0, stream>>>(out2, c1w, c1b, c2w, c2b, o2buf);
  k_final<<<512, 64, 0, stream>>>(o2buf, fcw, fcb, ipsum, ctxbuf, out);
}

// Round 7
// 243.316 us; speedup vs baseline: 1.1129x; 1.0897x over previous
//
#include <hip/hip_runtime.h>

typedef unsigned short ushort;
typedef unsigned int uint;
typedef __attribute__((ext_vector_type(8))) short short8v;
typedef __attribute__((ext_vector_type(4))) float floatx4;

// ---------------- problem constants ----------------
#define DIMK   8192
#define NPER   512
#define NROWS  2048
#define NCOLS  128
#define KSPLIT 8
#define KCHUNK 1024          // DIMK / KSPLIT
#define BK     64
#define BM     64
#define NIT    16            // KCHUNK / BK
#define SLICE_ELEMS 4194304.0

// ---------------- ws layout (bytes) ----------------
static const size_t STATS_OFF = 0;                                    // 16 doubles
static const size_t O2_OFF    = 128;                                  // 512 f32 (zeroed with stats)
static const size_t WB_OFF    = 4096;
static const size_t WB_BYTES  = (size_t)2 * 128 * DIMK * 2;           // 4 MB bf16 weights
static const size_t P_OFF     = WB_OFF + WB_BYTES;
static const size_t P_BYTES   = (size_t)2 * KSPLIT * NROWS * NCOLS * 4;  // 16.8 MB
static const size_t OUT2_OFF  = P_OFF + P_BYTES;                      // 512*512 f32
static const size_t IPSUM_OFF = OUT2_OFF + (size_t)512 * 512 * 4;     // 4*512 f32
static const size_t CTXB_OFF  = IPSUM_OFF + (size_t)4 * 512 * 4;      // 2048*64 f32
static const size_t WS_NEED   = CTXB_OFF + (size_t)2048 * 64 * 4;

__device__ __forceinline__ ushort f2bf(float x) {   // RNE f32->bf16
  uint u = __float_as_uint(x);
  return (ushort)((u + 0x7FFFu + ((u >> 16) & 1u)) >> 16);
}

// ---------------- K1: LN statistics (blocks 0..2047) + W->bf16 (blocks 2048..3071) ----------------
__global__ __launch_bounds__(256) void k_stats(const float* __restrict__ pic,
                                               const float* __restrict__ ctx,
                                               const float* __restrict__ Wp,
                                               const float* __restrict__ Wc,
                                               double* __restrict__ stats,
                                               ushort* __restrict__ Wb) {
  const int bid = blockIdx.x;
  const int tid = threadIdx.x;
  if (bid >= 2048) {
    const size_t i = ((size_t)(bid - 2048) * 256 + tid) * 8;
    const size_t HALF = (size_t)128 * DIMK;
    const float* src = (i < HALF) ? (Wp + i) : (Wc + (i - HALF));
    float4 a = *(const float4*)src;
    float4 b = *(const float4*)(src + 4);
    short8v v;
    v[0] = (short)f2bf(a.x); v[1] = (short)f2bf(a.y);
    v[2] = (short)f2bf(a.z); v[3] = (short)f2bf(a.w);
    v[4] = (short)f2bf(b.x); v[5] = (short)f2bf(b.y);
    v[6] = (short)f2bf(b.z); v[7] = (short)f2bf(b.w);
    *(short8v*)&Wb[i] = v;
    return;
  }
  const int s = bid >> 8;
  const int c = bid & 255;
  const int t = s >> 2, h = s & 3;
  const float4* p4 = reinterpret_cast<const float4*>(
      (t ? ctx : pic) + (size_t)h * NPER * DIMK + (size_t)c * 16384) + tid;

  float4 v[16];
#pragma unroll
  for (int j = 0; j < 16; ++j) v[j] = p4[256 * j];
  __builtin_amdgcn_sched_barrier(0);

  float sA[4] = {0.f, 0.f, 0.f, 0.f};
  float qA[4] = {0.f, 0.f, 0.f, 0.f};
#pragma unroll
  for (int j = 0; j < 16; j += 4) {
#pragma unroll
    for (int u = 0; u < 4; ++u) {
      const float4 w = v[j + u];
      sA[u] += (w.x + w.y) + (w.z + w.w);
      qA[u] += (w.x * w.x + w.y * w.y) + (w.z * w.z + w.w * w.w);
    }
  }

  float sum = (sA[0] + sA[1]) + (sA[2] + sA[3]);
  float sq  = (qA[0] + qA[1]) + (qA[2] + qA[3]);
#pragma unroll
  for (int d = 1; d < 64; d <<= 1) {
    sum += __shfl_xor(sum, d);
    sq  += __shfl_xor(sq, d);
  }
  __shared__ float ps[4], pq[4];
  const int w = tid >> 6;
  if ((tid & 63) == 0) { ps[w] = sum; pq[w] = sq; }
  __syncthreads();
  if (tid == 0) {
    double S = (double)ps[0] + (double)ps[1] + (double)ps[2] + (double)ps[3];
    double Q = (double)pq[0] + (double)pq[1] + (double)pq[2] + (double)pq[3];
    atomicAdd(&stats[2 * s], S);
    atomicAdd(&stats[2 * s + 1], Q);
  }
}

// ---------------- K2: fused LN+spike+MFMA GEMM (split-K partials) ----------------
// grid (32 row-tiles, KSPLIT, 2) = 512 blocks, 256 threads = 4 waves (2x2 of 32x64)
// single barrier per K-step; C staged in LDS (UNIONED with staging bufs) for
// coalesced full-line stores.
__global__ __launch_bounds__(256, 3) void k_gemm(const float* __restrict__ pic,
                                                 const float* __restrict__ ctxin,
                                                 const float* __restrict__ gamma,
                                                 const float* __restrict__ lnbeta,
                                                 const ushort* __restrict__ Wb,
                                                 const double* __restrict__ stats,
                                                 float* __restrict__ P) {
  const int tid  = threadIdx.x;
  const int lane = tid & 63;
  const int wv   = tid >> 6;
  const int wm   = wv >> 1, wn = wv & 1;
  const int bx = blockIdx.x, ky = blockIdx.y, t = blockIdx.z;
  const float*  A  = t ? ctxin : pic;
  const ushort* Wt = Wb + (size_t)t * 128 * DIMK;
  const int row0 = bx * BM;

  const int sidx = t * 4 + (bx >> 3);        // 8 tiles of 64 rows per h
  double su = stats[2 * sidx], qu = stats[2 * sidx + 1];
  double dmean = su * (1.0 / SLICE_ELEMS);
  const float mean = (float)dmean;
  const float var  = (float)(qu * (1.0 / SLICE_ELEMS) - dmean * dmean);
  const float rstd = rsqrtf(var + 1e-5f);

  // 48 KB shared block: [0,16K) Asl[2], [16K,48K) Wsl[2]; Cst overlays [0,33.8K)
  __shared__ __align__(16) char smem[49152];
  ushort* AslB = (ushort*)smem;                       // buf stride BM*BK
  ushort* WslB = (ushort*)(smem + 2 * BM * BK * 2);   // buf stride 128*BK
  float (*Cst)[132] = (float (*)[132])smem;           // 64 x 132 f32

  const int k8 = (tid & 7) * 8;
  const int r0 = tid >> 3;        // 0..31

  const int kg8 = (lane >> 4) << 3;
  int abase[2], axor[2], bbase[4], bxor[4];
#pragma unroll
  for (int m = 0; m < 2; ++m) {
    const int ra = wm * 32 + m * 16 + (lane & 15);
    abase[m] = ra * BK; axor[m] = (ra & 7) << 3;
  }
#pragma unroll
  for (int n = 0; n < 4; ++n) {
    const int rb = wn * 64 + n * 16 + (lane & 15);
    bbase[n] = rb * BK; bxor[n] = (rb & 7) << 3;
  }

  floatx4 acc[2][4];
  floatx4 zz = {0.f, 0.f, 0.f, 0.f};
#pragma unroll
  for (int m = 0; m < 2; ++m)
#pragma unroll
    for (int n = 0; n < 4; ++n) acc[m][n] = zz;

  float4 xa[2][2]; uint4 xw[4];
  float4 g0, g1, bb0, bb1;

  auto LOAD = [&](int it) {
    const int kb = ky * KCHUNK + it * BK;
    const float* gp = gamma  + kb + k8;
    const float* bp = lnbeta + kb + k8;
    g0 = *(const float4*)gp;  g1 = *(const float4*)(gp + 4);
    bb0 = *(const float4*)bp; bb1 = *(const float4*)(bp + 4);
#pragma unroll
    for (int c = 0; c < 2; ++c) {
      const float* ap = A + (size_t)(row0 + r0 + c * 32) * DIMK + kb + k8;
      xa[c][0] = *(const float4*)ap;
      xa[c][1] = *(const float4*)(ap + 4);
    }
#pragma unroll
    for (int c = 0; c < 4; ++c)
      xw[c] = *(const uint4*)(Wt + (size_t)(r0 + c * 32) * DIMK + kb + k8);
  };

  auto WRITE = [&](int buf) {
#pragma unroll
    for (int c = 0; c < 2; ++c) {
      const int r = r0 + c * 32;
      float xs[8] = {xa[c][0].x, xa[c][0].y, xa[c][0].z, xa[c][0].w,
                     xa[c][1].x, xa[c][1].y, xa[c][1].z, xa[c][1].w};
      float gs[8] = {g0.x, g0.y, g0.z, g0.w, g1.x, g1.y, g1.z, g1.w};
      float bs[8] = {bb0.x, bb0.y, bb0.z, bb0.w, bb1.x, bb1.y, bb1.z, bb1.w};
      short8v sv;
#pragma unroll
      for (int j = 0; j < 8; ++j)
        sv[j] = (short)(((xs[j] - mean) * rstd * gs[j] + bs[j] > 1.0f) ? 0x3F80 : 0);
      *(short8v*)&AslB[buf * (BM * BK) + r * BK + (k8 ^ ((r & 7) << 3))] = sv;
    }
#pragma unroll
    for (int c = 0; c < 4; ++c) {
      const int r = r0 + c * 32;
      *(uint4*)&WslB[buf * (128 * BK) + r * BK + (k8 ^ ((r & 7) << 3))] = xw[c];
    }
  };

  auto COMPUTE = [&](int buf) {
#pragma unroll
    for (int ks = 0; ks < 2; ++ks) {
      short8v af[2], bfr[4];
#pragma unroll
      for (int m = 0; m < 2; ++m)
        af[m] = *(const short8v*)&AslB[buf * (BM * BK) + abase[m] + ((ks * 32 + kg8) ^ axor[m])];
#pragma unroll
      for (int n = 0; n < 4; ++n)
        bfr[n] = *(const short8v*)&WslB[buf * (128 * BK) + bbase[n] + ((ks * 32 + kg8) ^ bxor[n])];
#pragma unroll
      for (int m = 0; m < 2; ++m)
#pragma unroll
        for (int n = 0; n < 4; ++n)
          acc[m][n] = __builtin_amdgcn_mfma_f32_16x16x32_bf16(af[m], bfr[n], acc[m][n], 0, 0, 0);
    }
  };

  LOAD(0);
  WRITE(0);
  __syncthreads();
#pragma unroll 2
  for (int it = 0; it < NIT - 1; ++it) {
    LOAD(it + 1);
    COMPUTE(it & 1);
    WRITE((it + 1) & 1);
    __syncthreads();
  }
  COMPUTE((NIT - 1) & 1);
  __syncthreads();   // all ds_reads done before Cst overlays the staging bufs

  // stage C in LDS (C/D layout: col = lane&15, row = (lane>>4)*4 + j),
  // then store full 512B rows coalesced.
#pragma unroll
  for (int m = 0; m < 2; ++m) {
    const int gr = wm * 32 + m * 16 + ((lane >> 4) << 2);
#pragma unroll
    for (int n = 0; n < 4; ++n) {
      const int gc = wn * 64 + n * 16 + (lane & 15);
#pragma unroll
      for (int j = 0; j < 4; ++j)
        Cst[gr + j][gc] = acc[m][n][j];
    }
  }
  __syncthreads();
  float* Pt = P + ((size_t)(t * KSPLIT + ky) * NROWS + row0) * NCOLS;
  const int rr = tid >> 2;            // 0..63
  const int cq = (tid & 3) * 32;      // 0,32,64,96
  float* dst = Pt + (size_t)rr * NCOLS + cq;
#pragma unroll
  for (int i = 0; i < 8; ++i)
    *(float4*)(dst + i * 4) = *(const float4*)&Cst[rr][cq + i * 4];
}

// ---------------- K3: per-row epilogue, vectorized (8 rows/block) ----------------
__global__ __launch_bounds__(256) void k_row(const float* __restrict__ P,
                                             const float* __restrict__ b_pic,
                                             const float* __restrict__ b_ctx,
                                             float* __restrict__ out2,
                                             float* __restrict__ ipsum,
                                             float* __restrict__ ctxbuf) {
  const int tid = threadIdx.x;
  const int q = tid >> 5;
  const int u = tid & 31;
  const int r = blockIdx.x * 8 + q;
  const int o4 = u * 4;

  float4 ip = ((const float4*)b_pic)[u];
  float4 cv = ((const float4*)b_ctx)[u];
#pragma unroll
  for (int ks = 0; ks < KSPLIT; ++ks) {
    const float4 a = *(const float4*)&P[((size_t)ks * NROWS + r) * NCOLS + o4];
    const float4 b = *(const float4*)&P[((size_t)(KSPLIT + ks) * NROWS + r) * NCOLS + o4];
    ip.x += a.x; ip.y += a.y; ip.z += a.z; ip.w += a.w;
    cv.x += b.x; cv.y += b.y; cv.z += b.z; cv.w += b.w;
  }
  ip.x *= 0.125f; ip.y *= 0.125f; ip.z *= 0.125f; ip.w *= 0.125f;

  float clo = (u < 16) ? (cv.x + cv.y) + (cv.z + cv.w) : 0.f;
  float chi = (u >= 16) ? (cv.x + cv.y) + (cv.z + cv.w) : 0.f;
  float ipp = (ip.x + ip.y) + (ip.z + ip.w);
#pragma unroll
  for (int d = 1; d < 32; d <<= 1) {
    clo += __shfl_xor(clo, d);
    chi += __shfl_xor(chi, d);
    ipp += __shfl_xor(ipp, d);
  }
  const float ic_s = clo, v_s = chi;
  if (u == 0) ipsum[r] = ipp;

  float4 sim;
  sim.x = ip.x * ic_s; sim.y = ip.y * ic_s; sim.z = ip.z * ic_s; sim.w = ip.w * ic_s;
  float m = fmaxf(fmaxf(sim.x, sim.y), fmaxf(sim.z, sim.w));
#pragma unroll
  for (int d = 1; d < 32; d <<= 1) m = fmaxf(m, __shfl_xor(m, d));
  float4 e;
  e.x = __expf(sim.x - m); e.y = __expf(sim.y - m);
  e.z = __expf(sim.z - m); e.w = __expf(sim.w - m);
  float es = (e.x + e.y) + (e.z + e.w);
#pragma unroll
  for (int d = 1; d < 32; d <<= 1) es += __shfl_xor(es, d);
  const float sc = v_s / es;
  float4 outv;
  outv.x = e.x * sc; outv.y = e.y * sc; outv.z = e.z * sc; outv.w = e.w * sc;

  const int hh = r >> 9, n = r & 511;
  *(float4*)&out2[(size_t)n * 512 + hh * 128 + o4] = outv;
  if (u < 16) *(float4*)&ctxbuf[(size_t)r * 64 + o4] = cv;
}

// ---------------- K4: conv chain as w_eff matvec (8 blocks, atomic) ----------------
__global__ __launch_bounds__(512) void k_mid(const float* __restrict__ out2,
                                             const float* __restrict__ c1w,
                                             const float* __restrict__ c1b,
                                             const float* __restrict__ c2w,
                                             const float* __restrict__ c2b,
                                             float* __restrict__ o2buf) {
  const int b = blockIdx.x;
  const int tid = threadIdx.x;
  __shared__ float wsh[64];
  __shared__ float c2s[32];
  if (tid < 32) c2s[tid] = c2w[tid];
  __syncthreads();
  if (tid < 64) {
    const int n = b * 64 + tid;
    float a = 0.f;
#pragma unroll
    for (int o = 0; o < 32; ++o) a += c2s[o] * c1w[o * 512 + n];
    wsh[tid] = a;
  }
  __syncthreads();
  float acc = 0.f;
#pragma unroll 8
  for (int ucnt = 0; ucnt < 64; ++ucnt)
    acc += out2[(size_t)(b * 64 + ucnt) * 512 + tid] * wsh[ucnt];
  if (b == 0) {
    float beff = c2b[0];
#pragma unroll
    for (int o = 0; o < 32; ++o) beff += c2s[o] * c1b[o];
    acc += beff;
  }
  atomicAdd(&o2buf[tid], acc);
}

// ---------------- K5: fc matvec + broadcast + interp + relu + ic_sum ----------------
__global__ __launch_bounds__(64) void k_final(const float* __restrict__ o2buf,
                                              const float* __restrict__ fcw,
                                              const float* __restrict__ fcb,
                                              const float* __restrict__ ipsum,
                                              const float* __restrict__ ctxbuf,
                                              float* __restrict__ out) {
  const int i = blockIdx.x;
  const int j = threadIdx.x;
  float a = 0.f;
#pragma unroll
  for (int uu = 0; uu < 8; ++uu) {
    const int k = j * 8 + uu;
    a += o2buf[k] * fcw[(size_t)i * 512 + k];
  }
#pragma unroll
  for (int d = 1; d < 64; d <<= 1) a += __shfl_xor(a, d);
  const float o3 = a + fcb[i];

  float src = (j + 0.5f) * (4.0f / 64.0f) - 0.5f;
  src = fmaxf(src, 0.0f);
  int i0 = (int)floorf(src);
  if (i0 > 3) i0 = 3;
  const int i1 = (i0 + 1 < 3) ? i0 + 1 : 3;
  const float w = src - (float)i0;

  const float v0 = o3 + ipsum[i0 * 512 + i];
  const float v1 = o3 + ipsum[i1 * 512 + i];
  float v = v0 * (1.0f - w) + v1 * w;
  v = fmaxf(v, 0.0f);

  float ics = 0.f;
#pragma unroll
  for (int hh2 = 0; hh2 < 4; ++hh2) ics += ctxbuf[((size_t)hh2 * 512 + i) * 64 + j];
  out[(size_t)i * 64 + j] = fmaxf(v + ics, 0.0f);
}

// ---------------- launch ----------------
extern "C" void kernel_launch(void* const* d_in, const int* in_sizes, int n_in,
                              void* d_out, int out_size, void* d_ws, size_t ws_size,
                              hipStream_t stream) {
  const float* pic    = (const float*)d_in[0];
  const float* ctx    = (const float*)d_in[1];
  const float* gamma  = (const float*)d_in[2];
  const float* lnbeta = (const float*)d_in[3];
  const float* Wp     = (const float*)d_in[4];
  const float* bp     = (const float*)d_in[5];
  const float* Wc     = (const float*)d_in[6];
  const float* bc     = (const float*)d_in[7];
  const float* c1w    = (const float*)d_in[8];
  const float* c1b    = (const float*)d_in[9];
  const float* c2w    = (const float*)d_in[10];
  const float* c2b    = (const float*)d_in[11];
  const float* fcw    = (const float*)d_in[12];
  const float* fcb    = (const float*)d_in[13];
  float* out = (float*)d_out;

  if (ws_size < WS_NEED) return;

  char* ws = (char*)d_ws;
  double* stats = (double*)(ws + STATS_OFF);
  float* o2buf  = (float*)(ws + O2_OFF);
  ushort* Wb    = (ushort*)(ws + WB_OFF);
  float* P      = (float*)(ws + P_OFF);
  float* out2   = (float*)(ws + OUT2_OFF);
  float* ipsum  = (float*)(ws + IPSUM_OFF);
  float* ctxbuf = (float*)(ws + CTXB_OFF);

  hipMemsetAsync(ws, 0, 128 + 512 * 4, stream);   // stats + o2buf
  k_stats<<<3072, 256, 0, stream>>>(pic, ctx, Wp, Wc, stats, Wb);
  k_gemm<<<dim3(32, KSPLIT, 2), 256, 0, stream>>>(pic, ctx, gamma, lnbeta, Wb, stats, P);
  k_row<<<256, 256, 0, stream>>>(P, bp, bc, out2, ipsum, ctxbuf);
  k_mid<<<8, 512, 0, stream>>>(out2, c1w, c1b, c2w, c2b, o2buf);
  k_final<<<512, 64, 0, stream>>>(o2buf, fcw, fcb, ipsum, ctxbuf, out);
}